// Round 3
// baseline (151.123 us; speedup 1.0000x reference)
//
#include <hip/hip_runtime.h>
#include <hip/hip_bf16.h>

#define SIZE 4096
#define BM 256
#define BK 64
#define NT (SIZE / BK)     // 64 K-tiles
#define NBG (SIZE / BM)    // 16x16 grid of 256^2 tiles

typedef __bf16 bf16x8 __attribute__((ext_vector_type(8)));
typedef float f32x4 __attribute__((ext_vector_type(4)));

// ---------------------------------------------------------------------------
// async global->LDS, 16B/lane: LDS dest = wave-uniform base + lane*16 (HW).
// ---------------------------------------------------------------------------
__device__ __forceinline__ void gload_lds16(const void* gsrc, void* ldst) {
  __builtin_amdgcn_global_load_lds(
      (const __attribute__((address_space(1))) unsigned int*)gsrc,
      (__attribute__((address_space(3))) unsigned int*)ldst, 16, 0, 0);
}

// ---------------------------------------------------------------------------
// Kernel 1: build L (bf16). One 256-thread block per row; block-wide prefix
// product over v = 1 - tanh^2 (fp32, matches reference underflow).
// ---------------------------------------------------------------------------
__global__ __launch_bounds__(256) void build_L(const float* __restrict__ p,
                                               __bf16* __restrict__ Lb) {
  const int row = blockIdx.x;
  const int tid = threadIdx.x;
  const int lane = tid & 63;
  const int wid = tid >> 6;
  const long base = (long)row * (row - 1) / 2;

  __shared__ float wtot[4];
  float carry = 1.0f;

  for (int j0 = 0; j0 < SIZE; j0 += 256) {
    if (j0 > row) {
      Lb[(size_t)row * SIZE + j0 + tid] = (__bf16)0.0f;
      continue;
    }
    const int j = j0 + tid;
    float t, v;
    if (j < row) {
      t = tanhf(p[base + j]);
      v = 1.0f - t * t;
    } else {
      t = (j == row) ? 1.0f : 0.0f;
      v = 1.0f;
    }
    float incl = v;
#pragma unroll
    for (int off = 1; off < 64; off <<= 1) {
      float o = __shfl_up(incl, off, 64);
      if (lane >= off) incl *= o;
    }
    if (lane == 63) wtot[wid] = incl;
    __syncthreads();
    float pre = carry;
    for (int w = 0; w < wid; ++w) pre *= wtot[w];
    float excl = __shfl_up(incl, 1, 64);
    if (lane == 0) excl = 1.0f;
    const float s = pre * excl;
    Lb[(size_t)row * SIZE + j] = (__bf16)(t * sqrtf(s));
    const float tot = wtot[0] * wtot[1] * wtot[2] * wtot[3];
    __syncthreads();
    carry *= tot;
  }
}

// ---------------------------------------------------------------------------
// Kernel 2: C = L*L^T, 256x256 tile, BK=64, 8 waves (2Mx4N), 4-phase/K-tile
// pipelined schedule (m201 template). LDS halves are K-split [kh][256][32]
// (64B rows: contiguous for linear global_load_lds, bank-floor for
// ds_read_b128). Counted vmcnt(6) gate once per K-tile; 1.75 tiles in flight.
// ---------------------------------------------------------------------------
__global__ __launch_bounds__(512, 1) void syrk8(const __bf16* __restrict__ Lb,
                                                float* __restrict__ C) {
  // [buf][ab][kh][row][k] : 2*2*2*256*32*2B = 128 KiB
  __shared__ __bf16 lds[2][2][2][256][32];

  // XCD-chunk swizzle (bijective: 256 % 8 == 0): each XCD owns 2 bi-rows.
  const int bid0 = blockIdx.x;
  const int bid = (bid0 & 7) * 32 + (bid0 >> 3);
  const int bi = bid >> 4, bj = bid & 15;

  const int tid = threadIdx.x;
  const int lane = tid & 63;
  const int wid = tid >> 6;  // 0..7
  const int wm = wid >> 2;   // 0..1 : rows wm*128..+127
  const int wn = wid & 3;    // 0..3 : cols wn*64..+63
  const int r16 = lane & 15;
  const int kg = lane >> 4;

  const size_t rowA0 = (size_t)bi * 256;
  const size_t rowB0 = (size_t)bj * 256;

  // staging: wave stages 16 rows (64B each) per issue, 2 issues per half-tile
  const int srow = wid * 32 + (lane >> 2);
  const int schunk = lane & 3;

  // half h (global): tile = h>>2; sub = h&3 -> [A-kh0, B-kh0, A-kh1, B-kh1]
  auto stage = [&](int h) {
    if (h >= 4 * NT) return;
    const int tile = h >> 2, sub = h & 3;
    const int ab = sub & 1, kh = sub >> 1, buf = tile & 1;
    const size_t grow0 = ab ? rowB0 : rowA0;
    const int gk = tile * BK + kh * 32;
    const __bf16* gsrc = Lb + (grow0 + srow) * SIZE + gk + schunk * 8;
    __bf16* base = &lds[buf][ab][kh][0][0];
#pragma unroll
    for (int q = 0; q < 2; ++q)
      gload_lds16(gsrc + (size_t)q * 16 * SIZE, base + (wid * 32 + q * 16) * 32);
  };

  f32x4 acc[8][4] = {};

  // prologue: tile0 (4 halves) + tile1's first 3 halves
  for (int h = 0; h < 7; ++h) stage(h);
  asm volatile("s_waitcnt vmcnt(6)" ::: "memory");  // tile0 landed
  __builtin_amdgcn_s_barrier();

  for (int t = 0; t < NT; ++t) {
    const int buf = t & 1;
    bf16x8 af[8], bf[2];
#pragma unroll
    for (int i = 0; i < 4; ++i) {  // phase: (kh, nh) = (i>>1, i&1)
      const int kh = i >> 1, nh = i & 1;
      if (nh == 0) {
#pragma unroll
        for (int m = 0; m < 8; ++m)
          af[m] = *(const bf16x8*)&lds[buf][0][kh][wm * 128 + m * 16 + r16][kg * 8];
      }
#pragma unroll
      for (int n = 0; n < 2; ++n)
        bf[n] = *(const bf16x8*)&lds[buf][1][kh][wn * 64 + (nh * 2 + n) * 16 + r16][kg * 8];

      stage(4 * t + 7 + i);  // 1 half-tile prefetch per phase

      if (i == 3) {  // once per K-tile: gate next tile's data
        if (t == NT - 2)
          asm volatile("s_waitcnt vmcnt(0)" ::: "memory");
        else if (t < NT - 2)
          asm volatile("s_waitcnt vmcnt(6)" ::: "memory");
      }
      __builtin_amdgcn_s_barrier();
      asm volatile("s_waitcnt lgkmcnt(0)" ::: "memory");
      __builtin_amdgcn_sched_barrier(0);
      __builtin_amdgcn_s_setprio(1);
#pragma unroll
      for (int m = 0; m < 8; ++m)
#pragma unroll
        for (int n = 0; n < 2; ++n)
          acc[m][nh * 2 + n] = __builtin_amdgcn_mfma_f32_16x16x32_bf16(
              af[m], bf[n], acc[m][nh * 2 + n], 0, 0, 0);
      __builtin_amdgcn_s_setprio(0);
      __builtin_amdgcn_s_barrier();
    }
  }

  // C/D layout (m89): col = lane&15, row = kg*4 + reg
  float* Cp = C + (rowA0 + wm * 128) * (size_t)SIZE + rowB0 + wn * 64;
#pragma unroll
  for (int m = 0; m < 8; ++m)
#pragma unroll
    for (int n = 0; n < 4; ++n)
#pragma unroll
      for (int j = 0; j < 4; ++j)
        Cp[(size_t)(m * 16 + kg * 4 + j) * SIZE + n * 16 + r16] = acc[m][n][j];
}

// ---------------------------------------------------------------------------
extern "C" void kernel_launch(void* const* d_in, const int* in_sizes, int n_in,
                              void* d_out, int out_size, void* d_ws, size_t ws_size,
                              hipStream_t stream) {
  const float* p = (const float*)d_in[0];
  float* C = (float*)d_out;
  __bf16* Lb = (__bf16*)d_ws;  // 32 MB scratch

  build_L<<<SIZE, 256, 0, stream>>>(p, Lb);
  syrk8<<<NBG * NBG, 512, 0, stream>>>(Lb, C);
}

// Round 4
// 137.071 us; speedup vs baseline: 1.1025x; 1.1025x over previous
//
#include <hip/hip_runtime.h>
#include <hip/hip_bf16.h>

#define SIZE 4096
#define BM 256
#define BK 64
#define NT (SIZE / BK)     // 64 K-tiles
#define NBG (SIZE / BM)    // 16x16 grid of 256^2 tiles

typedef __bf16 bf16x8 __attribute__((ext_vector_type(8)));
typedef float f32x4 __attribute__((ext_vector_type(4)));

// ---------------------------------------------------------------------------
// async global->LDS, 16B/lane: LDS dest = wave-uniform base + lane*16 (HW).
// ---------------------------------------------------------------------------
__device__ __forceinline__ void gload_lds16(const void* gsrc, void* ldst) {
  __builtin_amdgcn_global_load_lds(
      (const __attribute__((address_space(1))) unsigned int*)gsrc,
      (__attribute__((address_space(3))) unsigned int*)ldst, 16, 0, 0);
}

// ---------------------------------------------------------------------------
// Kernel 1: build L (bf16). One 256-thread block per row; block-wide prefix
// product over v = 1 - tanh^2 (fp32, matches reference underflow).
// ---------------------------------------------------------------------------
__global__ __launch_bounds__(256) void build_L(const float* __restrict__ p,
                                               __bf16* __restrict__ Lb) {
  const int row = blockIdx.x;
  const int tid = threadIdx.x;
  const int lane = tid & 63;
  const int wid = tid >> 6;
  const long base = (long)row * (row - 1) / 2;

  __shared__ float wtot[4];
  float carry = 1.0f;

  for (int j0 = 0; j0 < SIZE; j0 += 256) {
    if (j0 > row) {
      Lb[(size_t)row * SIZE + j0 + tid] = (__bf16)0.0f;
      continue;
    }
    const int j = j0 + tid;
    float t, v;
    if (j < row) {
      t = tanhf(p[base + j]);
      v = 1.0f - t * t;
    } else {
      t = (j == row) ? 1.0f : 0.0f;
      v = 1.0f;
    }
    float incl = v;
#pragma unroll
    for (int off = 1; off < 64; off <<= 1) {
      float o = __shfl_up(incl, off, 64);
      if (lane >= off) incl *= o;
    }
    if (lane == 63) wtot[wid] = incl;
    __syncthreads();
    float pre = carry;
    for (int w = 0; w < wid; ++w) pre *= wtot[w];
    float excl = __shfl_up(incl, 1, 64);
    if (lane == 0) excl = 1.0f;
    const float s = pre * excl;
    Lb[(size_t)row * SIZE + j] = (__bf16)(t * sqrtf(s));
    const float tot = wtot[0] * wtot[1] * wtot[2] * wtot[3];
    __syncthreads();
    carry *= tot;
  }
}

// ---------------------------------------------------------------------------
// Kernel 2: C = L*L^T, 256x256 tile, BK=64, 8 waves (2Mx4N), 4-phase/K-tile
// pipelined schedule (m201 template). LDS halves K-split [kh][256][32].
// T2 swizzle: 16B chunk c within a 64B row holds global chunk c^((row>>1)&3)
// -> ds_read_b128 slot coverage is 2-per-slot (bank-conflict-free, m136).
// Both-sides rule (21): linear LDS dest + inverse-permuted GLOBAL source +
// same permutation on the read. Both permutations are per-lane constants
// ((lane&3)^((lane>>3)&3) staging; kg^((r16>>1)&3) reading) - zero loop VALU.
// ---------------------------------------------------------------------------
__global__ __launch_bounds__(512, 1) void syrk8(const __bf16* __restrict__ Lb,
                                                float* __restrict__ C) {
  // [buf][ab][kh][row][k] : 2*2*2*256*32*2B = 128 KiB
  __shared__ __bf16 lds[2][2][2][256][32];

  // XCD-chunk swizzle (bijective: 256 % 8 == 0): each XCD owns 2 bi-rows.
  const int bid0 = blockIdx.x;
  const int bid = (bid0 & 7) * 32 + (bid0 >> 3);
  const int bi = bid >> 4, bj = bid & 15;

  const int tid = threadIdx.x;
  const int lane = tid & 63;
  const int wid = tid >> 6;  // 0..7
  const int wm = wid >> 2;   // 0..1 : rows wm*128..+127
  const int wn = wid & 3;    // 0..3 : cols wn*64..+63
  const int r16 = lane & 15;
  const int kg = lane >> 4;
  // swizzled chunk for LDS reads: row bits 1-2 == r16 bits 1-2 always
  const int rdk = (kg ^ ((r16 >> 1) & 3)) * 8;

  const size_t rowA0 = (size_t)bi * 256;
  const size_t rowB0 = (size_t)bj * 256;

  // staging: wave stages 16 rows (64B each) per issue, 2 issues per half-tile
  const int srow = wid * 32 + (lane >> 2);
  const int schunk = (lane & 3) ^ ((lane >> 3) & 3);  // inverse-swz source

  // half h (global): tile = h>>2; sub = h&3 -> [A-kh0, B-kh0, A-kh1, B-kh1]
  auto stage = [&](int h) {
    if (h >= 4 * NT) return;
    const int tile = h >> 2, sub = h & 3;
    const int ab = sub & 1, kh = sub >> 1, buf = tile & 1;
    const size_t grow0 = ab ? rowB0 : rowA0;
    const int gk = tile * BK + kh * 32;
    const __bf16* gsrc = Lb + (grow0 + srow) * SIZE + gk + schunk * 8;
    __bf16* base = &lds[buf][ab][kh][0][0];
#pragma unroll
    for (int q = 0; q < 2; ++q)
      gload_lds16(gsrc + (size_t)q * 16 * SIZE, base + (wid * 32 + q * 16) * 32);
  };

  f32x4 acc[8][4] = {};

  // prologue: tile0 (4 halves) + tile1's first 3 halves
  for (int h = 0; h < 7; ++h) stage(h);
  asm volatile("s_waitcnt vmcnt(6)" ::: "memory");  // tile0 landed
  __builtin_amdgcn_s_barrier();

  for (int t = 0; t < NT; ++t) {
    const int buf = t & 1;
    bf16x8 af[8], bf[2];
#pragma unroll
    for (int i = 0; i < 4; ++i) {  // phase: (kh, nh) = (i>>1, i&1)
      const int kh = i >> 1, nh = i & 1;
      if (nh == 0) {
#pragma unroll
        for (int m = 0; m < 8; ++m)
          af[m] = *(const bf16x8*)&lds[buf][0][kh][wm * 128 + m * 16 + r16][rdk];
      }
#pragma unroll
      for (int n = 0; n < 2; ++n)
        bf[n] = *(const bf16x8*)&lds[buf][1][kh][wn * 64 + (nh * 2 + n) * 16 + r16][rdk];

      stage(4 * t + 7 + i);  // 1 half-tile prefetch per phase

      if (i == 3) {  // once per K-tile: gate next tile's data
        if (t == NT - 2)
          asm volatile("s_waitcnt vmcnt(0)" ::: "memory");
        else if (t < NT - 2)
          asm volatile("s_waitcnt vmcnt(6)" ::: "memory");
      }
      __builtin_amdgcn_s_barrier();
      asm volatile("s_waitcnt lgkmcnt(0)" ::: "memory");
      __builtin_amdgcn_sched_barrier(0);
      __builtin_amdgcn_s_setprio(1);
#pragma unroll
      for (int m = 0; m < 8; ++m)
#pragma unroll
        for (int n = 0; n < 2; ++n)
          acc[m][nh * 2 + n] = __builtin_amdgcn_mfma_f32_16x16x32_bf16(
              af[m], bf[n], acc[m][nh * 2 + n], 0, 0, 0);
      __builtin_amdgcn_s_setprio(0);
      __builtin_amdgcn_s_barrier();
    }
  }

  // C/D layout (m89): col = lane&15, row = kg*4 + reg
  float* Cp = C + (rowA0 + wm * 128) * (size_t)SIZE + rowB0 + wn * 64;
#pragma unroll
  for (int m = 0; m < 8; ++m)
#pragma unroll
    for (int n = 0; n < 4; ++n)
#pragma unroll
      for (int j = 0; j < 4; ++j)
        Cp[(size_t)(m * 16 + kg * 4 + j) * SIZE + n * 16 + r16] = acc[m][n][j];
}

// ---------------------------------------------------------------------------
extern "C" void kernel_launch(void* const* d_in, const int* in_sizes, int n_in,
                              void* d_out, int out_size, void* d_ws, size_t ws_size,
                              hipStream_t stream) {
  const float* p = (const float*)d_in[0];
  float* C = (float*)d_out;
  __bf16* Lb = (__bf16*)d_ws;  // 32 MB scratch

  build_L<<<SIZE, 256, 0, stream>>>(p, Lb);
  syrk8<<<NBG * NBG, 512, 0, stream>>>(Lb, C);
}

// Round 5
// 128.346 us; speedup vs baseline: 1.1775x; 1.0680x over previous
//
#include <hip/hip_runtime.h>
#include <hip/hip_bf16.h>

#define SIZE 4096
#define BM 256
#define BK 64
#define NT (SIZE / BK)     // 64 K-tiles
#define NBG (SIZE / BM)    // 16x16 grid of 256^2 tiles

typedef __bf16 bf16x8 __attribute__((ext_vector_type(8)));
typedef __bf16 bf16x4 __attribute__((ext_vector_type(4)));
typedef float f32x4 __attribute__((ext_vector_type(4)));

// ---------------------------------------------------------------------------
// async global->LDS, 16B/lane: LDS dest = wave-uniform base + lane*16 (HW).
// ---------------------------------------------------------------------------
__device__ __forceinline__ void gload_lds16(const void* gsrc, void* ldst) {
  __builtin_amdgcn_global_load_lds(
      (const __attribute__((address_space(1))) unsigned int*)gsrc,
      (__attribute__((address_space(3))) unsigned int*)ldst, 16, 0, 0);
}

// ---------------------------------------------------------------------------
// Kernel 1: build L (bf16). One 256-thread block per row. 4 cols/thread
// (1024-col chunks): 4 iterations, 8 barriers total. Per-thread serial
// 4-element prefix product + wave shfl scan + cross-wave LDS totals.
// fp32 throughout (matches reference underflow).
// ---------------------------------------------------------------------------
__global__ __launch_bounds__(256) void build_L(const float* __restrict__ p,
                                               __bf16* __restrict__ Lb) {
  const int row = blockIdx.x;
  const int tid = threadIdx.x;
  const int lane = tid & 63;
  const int wid = tid >> 6;
  const long base = (long)row * (row - 1) / 2;

  __shared__ float wtot[4];
  float carry = 1.0f;

  for (int j0 = 0; j0 < SIZE; j0 += 1024) {
    const int jb = j0 + tid * 4;
    if (j0 > row) {  // block-uniform: whole chunk past the diagonal
      bf16x4 z = {(__bf16)0.0f, (__bf16)0.0f, (__bf16)0.0f, (__bf16)0.0f};
      *(bf16x4*)&Lb[(size_t)row * SIZE + jb] = z;
      continue;
    }
    float t[4], v[4];
#pragma unroll
    for (int e = 0; e < 4; ++e) {
      const int j = jb + e;
      if (j < row) {
        const float th = tanhf(p[base + j]);
        t[e] = th;
        v[e] = 1.0f - th * th;
      } else {
        t[e] = (j == row) ? 1.0f : 0.0f;  // diag z=1, upper 0
        v[e] = 1.0f;
      }
    }
    const float vt = v[0] * v[1] * v[2] * v[3];
    // wave-level inclusive scan (product) of per-thread totals
    float incl = vt;
#pragma unroll
    for (int off = 1; off < 64; off <<= 1) {
      float o = __shfl_up(incl, off, 64);
      if (lane >= off) incl *= o;
    }
    if (lane == 63) wtot[wid] = incl;
    __syncthreads();
    float pre = carry;
    for (int w = 0; w < wid; ++w) pre *= wtot[w];
    float excl = __shfl_up(incl, 1, 64);
    if (lane == 0) excl = 1.0f;
    float s = pre * excl;  // exclusive prefix up to jb
    bf16x4 out;
#pragma unroll
    for (int e = 0; e < 4; ++e) {
      out[e] = (__bf16)(t[e] * sqrtf(s));
      s *= v[e];
    }
    *(bf16x4*)&Lb[(size_t)row * SIZE + jb] = out;
    const float tot = wtot[0] * wtot[1] * wtot[2] * wtot[3];
    __syncthreads();  // wtot consumed before next chunk overwrites it
    carry *= tot;
  }
}

// ---------------------------------------------------------------------------
// Kernel 2: C = L*L^T, 256x256 tile, BK=64, 8 waves (2Mx4N), 4-phase/K-tile
// (m201 template). LDS halves K-split [kh][256][32]. T2 chunk-XOR swizzle
// (R4-verified: bank conflicts = 0). Phases split by (kh, m-half):
// ds_reads per phase = 8/4/8/4 (balanced, m201-style) instead of 10/2/10/2.
// Sync/vmcnt skeleton identical to the R4-passing kernel.
// ---------------------------------------------------------------------------
__global__ __launch_bounds__(512, 1) void syrk8(const __bf16* __restrict__ Lb,
                                                float* __restrict__ C) {
  // [buf][ab][kh][row][k] : 2*2*2*256*32*2B = 128 KiB
  __shared__ __bf16 lds[2][2][2][256][32];

  // XCD-chunk swizzle (bijective: 256 % 8 == 0): each XCD owns 2 bi-rows.
  const int bid0 = blockIdx.x;
  const int bid = (bid0 & 7) * 32 + (bid0 >> 3);
  const int bi = bid >> 4, bj = bid & 15;

  const int tid = threadIdx.x;
  const int lane = tid & 63;
  const int wid = tid >> 6;  // 0..7
  const int wm = wid >> 2;   // 0..1 : rows wm*128..+127
  const int wn = wid & 3;    // 0..3 : cols wn*64..+63
  const int r16 = lane & 15;
  const int kg = lane >> 4;
  // swizzled chunk for LDS reads (row bits 1-2 == r16 bits 1-2 always)
  const int rdk = (kg ^ ((r16 >> 1) & 3)) * 8;

  const size_t rowA0 = (size_t)bi * 256;
  const size_t rowB0 = (size_t)bj * 256;

  // staging: wave stages 16 rows (64B each) per issue, 2 issues per half-tile
  const int srow = wid * 32 + (lane >> 2);
  const int schunk = (lane & 3) ^ ((lane >> 3) & 3);  // inverse-swz source

  // half h (global): tile = h>>2; sub = h&3 -> [A-kh0, B-kh0, A-kh1, B-kh1]
  auto stage = [&](int h) {
    if (h >= 4 * NT) return;
    const int tile = h >> 2, sub = h & 3;
    const int ab = sub & 1, kh = sub >> 1, buf = tile & 1;
    const size_t grow0 = ab ? rowB0 : rowA0;
    const int gk = tile * BK + kh * 32;
    const __bf16* gsrc = Lb + (grow0 + srow) * SIZE + gk + schunk * 8;
    __bf16* base = &lds[buf][ab][kh][0][0];
#pragma unroll
    for (int q = 0; q < 2; ++q)
      gload_lds16(gsrc + (size_t)q * 16 * SIZE, base + (wid * 32 + q * 16) * 32);
  };

  f32x4 acc[8][4] = {};

  // prologue: tile0 (4 halves) + tile1's first 3 halves
  for (int h = 0; h < 7; ++h) stage(h);
  asm volatile("s_waitcnt vmcnt(6)" ::: "memory");  // tile0 landed
  __builtin_amdgcn_s_barrier();

  for (int t = 0; t < NT; ++t) {
    const int buf = t & 1;
    bf16x8 af[4], bf[4];
#pragma unroll
    for (int i = 0; i < 4; ++i) {  // phase: (kh, mh) = (i>>1, i&1)
      const int kh = i >> 1, mh = i & 1;
      if (mh == 0) {  // B-frags for this kh: live across both m-half phases
#pragma unroll
        for (int n = 0; n < 4; ++n)
          bf[n] = *(const bf16x8*)&lds[buf][1][kh][wn * 64 + n * 16 + r16][rdk];
      }
#pragma unroll
      for (int m = 0; m < 4; ++m)
        af[m] = *(const bf16x8*)&lds[buf][0][kh]
                                    [wm * 128 + (mh * 4 + m) * 16 + r16][rdk];

      stage(4 * t + 7 + i);  // 1 half-tile prefetch per phase

      if (i == 3) {  // once per K-tile: gate next tile's data
        if (t == NT - 2)
          asm volatile("s_waitcnt vmcnt(0)" ::: "memory");
        else if (t < NT - 2)
          asm volatile("s_waitcnt vmcnt(6)" ::: "memory");
      }
      __builtin_amdgcn_s_barrier();
      asm volatile("s_waitcnt lgkmcnt(0)" ::: "memory");
      __builtin_amdgcn_sched_barrier(0);
      __builtin_amdgcn_s_setprio(1);
#pragma unroll
      for (int m = 0; m < 4; ++m)
#pragma unroll
        for (int n = 0; n < 4; ++n)
          acc[mh * 4 + m][n] = __builtin_amdgcn_mfma_f32_16x16x32_bf16(
              af[m], bf[n], acc[mh * 4 + m][n], 0, 0, 0);
      __builtin_amdgcn_s_setprio(0);
      __builtin_amdgcn_s_barrier();
    }
  }

  // C/D layout (m89): col = lane&15, row = kg*4 + reg
  float* Cp = C + (rowA0 + wm * 128) * (size_t)SIZE + rowB0 + wn * 64;
#pragma unroll
  for (int m = 0; m < 8; ++m)
#pragma unroll
    for (int n = 0; n < 4; ++n)
#pragma unroll
      for (int j = 0; j < 4; ++j)
        Cp[(size_t)(m * 16 + kg * 4 + j) * SIZE + n * 16 + r16] = acc[m][n][j];
}

// ---------------------------------------------------------------------------
extern "C" void kernel_launch(void* const* d_in, const int* in_sizes, int n_in,
                              void* d_out, int out_size, void* d_ws, size_t ws_size,
                              hipStream_t stream) {
  const float* p = (const float*)d_in[0];
  float* C = (float*)d_out;
  __bf16* Lb = (__bf16*)d_ws;  // 32 MB scratch

  build_L<<<SIZE, 256, 0, stream>>>(p, Lb);
  syrk8<<<NBG * NBG, 512, 0, stream>>>(Lb, C);
}